// Round 13
// baseline (228.907 us; speedup 1.0000x reference)
//
#include <hip/hip_runtime.h>
#include <hip/hip_bf16.h>

typedef __bf16 bf16x8 __attribute__((ext_vector_type(8)));
typedef __bf16 bf16x4 __attribute__((ext_vector_type(4)));
typedef float f32x4 __attribute__((ext_vector_type(4)));
typedef float f32x16 __attribute__((ext_vector_type(16)));

__device__ __forceinline__ void gload16(void* lds, const void* g) {
  __builtin_amdgcn_global_load_lds((const __attribute__((address_space(1))) void*)g,
                                   (__attribute__((address_space(3))) void*)lds, 16, 0, 0);
}

// ---------------- merged weight cast+transpose: 4 matrices, one launch ----------------
__global__ __launch_bounds__(256)
void transpose4(const float* __restrict__ s0, __bf16* __restrict__ d0,
                const float* __restrict__ s1, __bf16* __restrict__ d1,
                const float* __restrict__ s2, __bf16* __restrict__ d2,
                const float* __restrict__ s3, __bf16* __restrict__ d3)
{
  __shared__ __bf16 tile[32][33];
  int id = blockIdx.x;
  const float* in; __bf16* out; int R, C, bx, by;
  if (id < 3072)      { in = s0; out = d0; R = 1024; C = 3072; bx = id % 96;  by = id / 96; }
  else if (id < 4096) { id -= 3072; in = s1; out = d1; R = 1024; C = 1024; bx = id % 32;  by = id / 32; }
  else if (id < 8192) { id -= 4096; in = s2; out = d2; R = 1024; C = 4096; bx = id % 128; by = id / 128; }
  else                { id -= 8192; in = s3; out = d3; R = 4096; C = 1024; bx = id % 32;  by = id / 32; }
  const int bc = bx * 32, br = by * 32;
  const int lx = threadIdx.x & 31, ly = threadIdx.x >> 5;
#pragma unroll
  for (int p = 0; p < 4; ++p)
    tile[ly + p * 8][lx] = (__bf16)in[(size_t)(br + ly + p * 8) * C + bc + lx];
  __syncthreads();
#pragma unroll
  for (int p = 0; p < 4; ++p)
    out[(size_t)(bc + ly + p * 8) * R + br + lx] = tile[lx][ly + p * 8];
}

// ---------------- V transpose (bf16): qkv [B*S][3072] -> vtg [BH][64][2048] ----------------
__global__ __launch_bounds__(256)
void vtrans(const __bf16* __restrict__ qkv, __bf16* __restrict__ vtg)
{
  __shared__ __bf16 tile[32][33];
  const int sx = blockIdx.x * 32;
  const int dy = blockIdx.y * 32;
  const int z = blockIdx.z;
  const int b = z >> 4, h = z & 15;
  const int lx = threadIdx.x & 31, ly = threadIdx.x >> 5;
  const __bf16* src = qkv + (size_t)b * 2048 * 3072 + 2048 + h * 64;
#pragma unroll
  for (int p = 0; p < 4; ++p)
    tile[ly + p * 8][lx] = src[(size_t)(sx + ly + p * 8) * 3072 + dy + lx];
  __syncthreads();
  __bf16* dst = vtg + (size_t)z * 64 * 2048;
#pragma unroll
  for (int p = 0; p < 4; ++p)
    dst[(size_t)(dy + ly + p * 8) * 2048 + sx + lx] = tile[lx][ly + p * 8];
}

// ---------------- elementwise cast fp32 -> bf16 ----------------
__global__ __launch_bounds__(256)
void cast_bf16(const float* __restrict__ in, __bf16* __restrict__ out)
{
  const int i = (blockIdx.x * 256 + threadIdx.x) * 4;
  float4 v = *(const float4*)(in + i);
  out[i] = (__bf16)v.x; out[i + 1] = (__bf16)v.y;
  out[i + 2] = (__bf16)v.z; out[i + 3] = (__bf16)v.w;
}

// ========= 2-phase dbuf GEMM with 32x32x16 MFMA, parametric BN (BK=64) ====================
// Per-wave out 64 x BN/2 as 2 x (BN/64) fragments of 32x32. A-operand: lane&31 = row,
// lane>>5 = k-half (8 bf16). C/D: col=lane&31 (B-frag), row=(reg&3)+8*(reg>>2)+4*(lane>>5).
// Swizzle unchanged: chunk c of row r holds logical c ^ (r&7); frag reads 2 lanes/bank.
template<int BN, bool OUT_BF16, bool RELU, bool RESID, bool RBF16, bool SPLIT>
__global__ __launch_bounds__(256)
void gemm_bt(const __bf16* __restrict__ A, const __bf16* __restrict__ Bt,
             const float* __restrict__ bias, const void* __restrict__ residv,
             void* __restrict__ C0v, void* __restrict__ C1v,
             int M, int N, int Kfull, int Ksub)
{
  constexpr int BK = 64;
  constexpr int NW2 = BN / 64;         // 32-col n-frags per wave
  constexpr int CH = BK / 8;
  __shared__ __bf16 As[2][128 * BK];
  __shared__ __bf16 Bs[2][BN * BK];
  const int tid = threadIdx.x;
  const int wave = tid >> 6, lane = tid & 63;
  const int l31 = lane & 31, hk = lane >> 5;
  const int row0 = blockIdx.x * 128, col0 = blockIdx.y * BN;
  const int z = SPLIT ? blockIdx.z : 0;
  const __bf16* Az = A + (size_t)z * Ksub;
  const __bf16* Bz = Bt + (size_t)z * Ksub;
  const int wr = wave >> 1, wc = wave & 1;
  f32x16 acc[2][NW2] = {};
  const int nk = Ksub / BK;

  auto STAGE = [&](int buf, int k0) {
#pragma unroll
    for (int r = 0; r < 128 * CH / 256; ++r) {
      const int seg = r * 256 + tid;
      const int row = seg / CH, cp = seg % CH;
      const int src = (cp ^ (row & 7)) * 8;
      gload16(&As[buf][(r * 256 + wave * 64) * 8], &Az[(size_t)(row0 + row) * Kfull + k0 + src]);
    }
#pragma unroll
    for (int r = 0; r < BN * CH / 256; ++r) {
      const int seg = r * 256 + tid;
      const int row = seg / CH, cp = seg % CH;
      const int src = (cp ^ (row & 7)) * 8;
      gload16(&Bs[buf][(r * 256 + wave * 64) * 8], &Bz[(size_t)(col0 + row) * Kfull + k0 + src]);
    }
  };

  STAGE(0, 0);
  __syncthreads();
  int cur = 0;
  for (int t = 0; t < nk; ++t) {
    if (t + 1 < nk) STAGE(cur ^ 1, (t + 1) * BK);
#pragma unroll
    for (int ks = 0; ks < 4; ++ks) {                 // 4 K-steps of 16
      bf16x8 af[2], bfr[NW2];
#pragma unroll
      for (int m = 0; m < 2; ++m) {
        const int row = wr * 64 + m * 32 + l31;
        af[m] = *(const bf16x8*)&As[cur][row * BK + (((2 * ks + hk) ^ (row & 7)) << 3)];
      }
#pragma unroll
      for (int n = 0; n < NW2; ++n) {
        const int row = wc * (BN / 2) + n * 32 + l31;
        bfr[n] = *(const bf16x8*)&Bs[cur][row * BK + (((2 * ks + hk) ^ (row & 7)) << 3)];
      }
#pragma unroll
      for (int m = 0; m < 2; ++m)
#pragma unroll
        for (int n = 0; n < NW2; ++n)
          acc[m][n] = __builtin_amdgcn_mfma_f32_32x32x16_bf16(af[m], bfr[n], acc[m][n], 0, 0, 0);
    }
    __syncthreads();
    cur ^= 1;
  }
#pragma unroll
  for (int n = 0; n < NW2; ++n) {
    const int col = col0 + wc * (BN / 2) + n * 32 + l31;
    float bv = 0.f;
    if (!SPLIT || z == 0) bv = bias[col];
#pragma unroll
    for (int m = 0; m < 2; ++m) {
#pragma unroll
      for (int reg = 0; reg < 16; ++reg) {
        const int rrow = row0 + wr * 64 + m * 32 + (reg & 3) + 8 * (reg >> 2) + 4 * hk;
        float v = acc[m][n][reg] + bv;
        const size_t idx = (size_t)rrow * N + col;
        if (RESID && (!SPLIT || z == 0)) {
          if (RBF16) v += (float)((const __bf16*)residv)[idx];
          else       v += ((const float*)residv)[idx];
        }
        if (SPLIT) {
          ((__bf16*)(z ? C1v : C0v))[idx] = (__bf16)v;
        } else {
          if (RELU)  v = fmaxf(v, 0.f);
          if (OUT_BF16) ((__bf16*)C0v)[idx] = (__bf16)v;
          else          ((float*)C0v)[idx] = v;
        }
      }
    }
  }
}

// ---------------- flash attention (causal), swapped-QK^T, no-max softmax ------------------
// grid (32 bh, 32 y); balanced qi permutation; 40 KB LDS -> 4 blocks/CU.
__global__ __launch_bounds__(256)
void attn_fwd(const __bf16* __restrict__ qkv, const __bf16* __restrict__ vtg,
              __bf16* __restrict__ ctx)
{
  constexpr int S = 2048, H = 1024, W3 = 3 * H;
  __shared__ __bf16 Ks[2][64 * 64];
  __shared__ __bf16 Vt[2][64 * 64];
  __shared__ __bf16 Ps[4][16 * 64];
  const int tid = threadIdx.x, wave = tid >> 6, lane = tid & 63;
  const int g = lane >> 4, l16 = lane & 15;
  const int perm = ((l16 & 7) << 1) | (l16 >> 3);
  const int bh = blockIdx.x;
  const int y = blockIdx.y, j = y & 7, m = y >> 3;
  const int qi = (m == 0) ? (31 - j) : (m == 1) ? (16 + j) : (m == 2) ? (15 - j) : j;
  const int b = bh >> 4, h = bh & 15;
  const size_t base = (size_t)b * S * W3;
  const __bf16* Qg = qkv + base;
  const __bf16* Kg = qkv + base + H;
  const __bf16* Vg = vtg + (size_t)bh * 64 * S;

  auto STAGE_KV = [&](int buf, int kv0) {
#pragma unroll
    for (int r = 0; r < 2; ++r) {
      const int seg = r * 256 + tid;
      const int row = seg >> 3;
      const int ko = ((seg & 7) ^ (row & 7)) * 8;
      gload16(&Ks[buf][(r * 256 + wave * 64) * 8], &Kg[(size_t)(kv0 + row) * W3 + h * 64 + ko]);
      gload16(&Vt[buf][(r * 256 + wave * 64) * 8], &Vg[(size_t)row * S + kv0 + ko]);
    }
  };

  const int q0 = qi * 64;
  const int qrow = q0 + wave * 16 + l16;
  bf16x8 qa[2];
#pragma unroll
  for (int kk = 0; kk < 2; ++kk)
    qa[kk] = *(const bf16x8*)&Qg[(size_t)qrow * W3 + h * 64 + kk * 32 + g * 8];

  f32x4 o[4] = {};
  float lsum = 0.f;
  const int nT = qi + 1;

  STAGE_KV(0, 0);
  __syncthreads();
  int cur = 0;

  for (int t = 0; t < nT; ++t) {
    const int kv0 = t * 64;
    if (t + 1 < nT) STAGE_KV(cur ^ 1, kv0 + 64);

    f32x4 s[4] = {};
    __builtin_amdgcn_s_setprio(1);
#pragma unroll
    for (int kk = 0; kk < 2; ++kk) {
      bf16x8 kb[4];
#pragma unroll
      for (int n = 0; n < 4; ++n) {
        const int row = n * 16 + l16;
        kb[n] = *(const bf16x8*)&Ks[cur][row * 64 + ((kk * 32 + g * 8) ^ ((row & 7) << 3))];
      }
#pragma unroll
      for (int n = 0; n < 4; ++n)
        s[n] = __builtin_amdgcn_mfma_f32_16x16x32_bf16(kb[n], qa[kk], s[n], 0, 0, 0);
    }
    __builtin_amdgcn_s_setprio(0);

    const bool diag = (t == nT - 1);
#pragma unroll
    for (int n = 0; n < 4; ++n) {
      float lp[4];
#pragma unroll
      for (int r = 0; r < 4; ++r) {
        const int ka = kv0 + n * 16 + g * 4 + r;
        float p = exp2f(s[n][r] * 0.18033688f);
        if (diag && ka > qrow) p = 0.f;
        lp[r] = p;
        lsum += p;
      }
      bf16x4 pk;
      pk[0] = (__bf16)lp[0]; pk[1] = (__bf16)lp[1];
      pk[2] = (__bf16)lp[2]; pk[3] = (__bf16)lp[3];
      *(bf16x4*)&Ps[wave][l16 * 64 + (((4 * n + g) ^ perm) << 2)] = pk;
    }

    __builtin_amdgcn_s_setprio(1);
#pragma unroll
    for (int kk = 0; kk < 2; ++kk) {
      const int hb = 8 * kk + 2 * g;
      bf16x4 p0 = *(const bf16x4*)&Ps[wave][l16 * 64 + ((hb ^ perm) << 2)];
      bf16x4 p1 = *(const bf16x4*)&Ps[wave][l16 * 64 + (((hb + 1) ^ perm) << 2)];
      bf16x8 pa = __builtin_shufflevector(p0, p1, 0, 1, 2, 3, 4, 5, 6, 7);
      bf16x8 vb[4];
#pragma unroll
      for (int n2 = 0; n2 < 4; ++n2) {
        const int row = n2 * 16 + l16;
        vb[n2] = *(const bf16x8*)&Vt[cur][row * 64 + ((kk * 32 + g * 8) ^ ((row & 7) << 3))];
      }
#pragma unroll
      for (int n2 = 0; n2 < 4; ++n2)
        o[n2] = __builtin_amdgcn_mfma_f32_16x16x32_bf16(pa, vb[n2], o[n2], 0, 0, 0);
    }
    __builtin_amdgcn_s_setprio(0);
    __syncthreads();
    cur ^= 1;
  }

  lsum += __shfl_xor(lsum, 16);
  lsum += __shfl_xor(lsum, 32);
#pragma unroll
  for (int r = 0; r < 4; ++r) {
    const float den = __shfl(lsum, g * 4 + r);
    const float inv = 1.f / den;
    const int qr = q0 + wave * 16 + g * 4 + r;
#pragma unroll
    for (int n2 = 0; n2 < 4; ++n2) {
      const int d = n2 * 16 + l16;
      ctx[(size_t)(b * S + qr) * H + h * 64 + d] = (__bf16)(o[n2][r] * inv);
    }
  }
}

// ---------------- LayerNorm over rows of 1024, fp32 input -------------------------------
template<bool WRITE_F32, bool WRITE_BF16>
__global__ __launch_bounds__(256)
void ln_kernel(const float* __restrict__ in,
               const float* __restrict__ gw, const float* __restrict__ bw,
               float* __restrict__ outf, __bf16* __restrict__ outb)
{
  const int row = blockIdx.x, tid = threadIdx.x;
  float4 xv = ((const float4*)(in + (size_t)row * 1024))[tid];
  float s = xv.x + xv.y + xv.z + xv.w;
  float s2 = xv.x * xv.x + xv.y * xv.y + xv.z * xv.z + xv.w * xv.w;
#pragma unroll
  for (int off = 32; off; off >>= 1) { s += __shfl_xor(s, off); s2 += __shfl_xor(s2, off); }
  __shared__ float ps[8];
  if ((tid & 63) == 0) { ps[tid >> 6] = s; ps[4 + (tid >> 6)] = s2; }
  __syncthreads();
  s = ps[0] + ps[1] + ps[2] + ps[3];
  s2 = ps[4] + ps[5] + ps[6] + ps[7];
  const float mean = s * (1.f / 1024.f);
  const float var = s2 * (1.f / 1024.f) - mean * mean;
  const float rs = rsqrtf(var + 1e-5f);
  const float4 gv = ((const float4*)gw)[tid];
  const float4 bv = ((const float4*)bw)[tid];
  float4 y;
  y.x = (xv.x - mean) * rs * gv.x + bv.x;
  y.y = (xv.y - mean) * rs * gv.y + bv.y;
  y.z = (xv.z - mean) * rs * gv.z + bv.z;
  y.w = (xv.w - mean) * rs * gv.w + bv.w;
  if (WRITE_F32)
    ((float4*)(outf + (size_t)row * 1024))[tid] = y;
  if (WRITE_BF16) {
    __bf16* ob = outb + (size_t)row * 1024 + tid * 4;
    ob[0] = (__bf16)y.x; ob[1] = (__bf16)y.y; ob[2] = (__bf16)y.z; ob[3] = (__bf16)y.w;
  }
}

// ---------------- LayerNorm summing two bf16 partial inputs -> fp32 out ------------------
__global__ __launch_bounds__(256)
void ln2b_kernel(const __bf16* __restrict__ in, const __bf16* __restrict__ in2,
                 const float* __restrict__ gw, const float* __restrict__ bw,
                 float* __restrict__ outf)
{
  const int row = blockIdx.x, tid = threadIdx.x;
  const bf16x4 a = ((const bf16x4*)(in + (size_t)row * 1024))[tid];
  const bf16x4 b = ((const bf16x4*)(in2 + (size_t)row * 1024))[tid];
  float4 xv;
  xv.x = (float)a[0] + (float)b[0];
  xv.y = (float)a[1] + (float)b[1];
  xv.z = (float)a[2] + (float)b[2];
  xv.w = (float)a[3] + (float)b[3];
  float s = xv.x + xv.y + xv.z + xv.w;
  float s2 = xv.x * xv.x + xv.y * xv.y + xv.z * xv.z + xv.w * xv.w;
#pragma unroll
  for (int off = 32; off; off >>= 1) { s += __shfl_xor(s, off); s2 += __shfl_xor(s2, off); }
  __shared__ float ps[8];
  if ((tid & 63) == 0) { ps[tid >> 6] = s; ps[4 + (tid >> 6)] = s2; }
  __syncthreads();
  s = ps[0] + ps[1] + ps[2] + ps[3];
  s2 = ps[4] + ps[5] + ps[6] + ps[7];
  const float mean = s * (1.f / 1024.f);
  const float var = s2 * (1.f / 1024.f) - mean * mean;
  const float rs = rsqrtf(var + 1e-5f);
  const float4 gv = ((const float4*)gw)[tid];
  const float4 bv = ((const float4*)bw)[tid];
  float4 y;
  y.x = (xv.x - mean) * rs * gv.x + bv.x;
  y.y = (xv.y - mean) * rs * gv.y + bv.y;
  y.z = (xv.z - mean) * rs * gv.z + bv.z;
  y.w = (xv.w - mean) * rs * gv.w + bv.w;
  ((float4*)(outf + (size_t)row * 1024))[tid] = y;
}

extern "C" void kernel_launch(void* const* d_in, const int* in_sizes, int n_in,
                              void* d_out, int out_size, void* d_ws, size_t ws_size,
                              hipStream_t stream)
{
  (void)in_sizes; (void)n_in; (void)out_size; (void)ws_size;
  const float* x     = (const float*)d_in[0];
  const float* qkv_w = (const float*)d_in[2];
  const float* qkv_b = (const float*)d_in[3];
  const float* out_w = (const float*)d_in[4];
  const float* out_b = (const float*)d_in[5];
  const float* w1    = (const float*)d_in[6];
  const float* b1    = (const float*)d_in[7];
  const float* w2    = (const float*)d_in[8];
  const float* b2    = (const float*)d_in[9];
  const float* ln1g  = (const float*)d_in[10];
  const float* ln1b  = (const float*)d_in[11];
  const float* ln2g  = (const float*)d_in[12];
  const float* ln2b  = (const float*)d_in[13];

  char* ws = (char*)d_ws;
  __bf16* wt_qkv = (__bf16*)(ws + 0);          // [3072][1024]  dead after QKV
  __bf16* wt_out = (__bf16*)(ws + 6291456);    // [1024][1024]  dead after out-proj
  __bf16* wt_w1  = (__bf16*)(ws + 8388608);    // [4096][1024]  dead after FFN1
  __bf16* wt_w2  = (__bf16*)(ws + 16777216);   // [1024][4096]  live through FFN2
  __bf16* xb     = (__bf16*)(ws + 25165824);   // x bf16, then ctx
  __bf16* big    = (__bf16*)(ws + 33554432);   // qkv, then h1
  float*  res    = (float*)(ws + 67108864);    // vtg, then res1, then FFN2 bf16 partial z=0
  __bf16* x1b    = (__bf16*)(ws + 100663296);  // ln1 out bf16 (FFN1 A + FFN2 resid)
  __bf16* vtg    = (__bf16*)res;               // [32][64][2048] (dead after attn)
  __bf16* pz0    = (__bf16*)res;               // FFN2 partial z=0 (8MB)
  __bf16* pz1    = (__bf16*)ws;                // FFN2 partial z=1 (8MB over dead weights)

  transpose4<<<12288, 256, 0, stream>>>(qkv_w, wt_qkv, out_w, wt_out, w1, wt_w1, w2, wt_w2);
  cast_bf16<<<4096, 256, 0, stream>>>(x, xb);

  // QKV: BN=128, grid 32x24
  gemm_bt<128, true, false, false, false, false><<<dim3(32, 24), 256, 0, stream>>>(
      xb, wt_qkv, qkv_b, nullptr, big, nullptr, 4096, 3072, 1024, 1024);
  // V -> V^T per (b,h)
  vtrans<<<dim3(64, 2, 32), 256, 0, stream>>>(big, vtg);
  // attention -> ctx (reuses xb); 1024 balanced blocks, 4/CU
  attn_fwd<<<dim3(32, 32), 256, 0, stream>>>(big, vtg, xb);
  // out-proj + residual(x fp32) -> res fp32 ; BN=64, grid 32x16
  gemm_bt<64, false, false, true, false, false><<<dim3(32, 16), 256, 0, stream>>>(
      xb, wt_out, out_b, x, res, nullptr, 4096, 1024, 1024, 1024);
  // LN1 -> x1b bf16 only
  ln_kernel<false, true><<<4096, 256, 0, stream>>>(res, ln1g, ln1b, nullptr, x1b);
  // FFN1 + ReLU: BN=128, grid 32x32 -> h1 bf16
  gemm_bt<128, true, true, false, false, false><<<dim3(32, 32), 256, 0, stream>>>(
      x1b, wt_w1, b1, nullptr, big, nullptr, 4096, 4096, 1024, 1024);
  // FFN2 + residual(x1b bf16): split-K=2, grid 32x8x2 -> bf16 partials pz0, pz1
  gemm_bt<128, false, false, true, true, true><<<dim3(32, 8, 2), 256, 0, stream>>>(
      big, wt_w2, b2, x1b, pz0, pz1, 4096, 1024, 4096, 2048);
  // LN2 (combines bf16 partials) -> d_out
  ln2b_kernel<<<4096, 256, 0, stream>>>(pz0, pz1, ln2g, ln2b, (float*)d_out);
}

// Round 15
// 219.888 us; speedup vs baseline: 1.0410x; 1.0410x over previous
//
#include <hip/hip_runtime.h>
#include <hip/hip_bf16.h>

typedef __bf16 bf16x8 __attribute__((ext_vector_type(8)));
typedef __bf16 bf16x4 __attribute__((ext_vector_type(4)));
typedef float f32x4 __attribute__((ext_vector_type(4)));

__device__ __forceinline__ void gload16(void* lds, const void* g) {
  __builtin_amdgcn_global_load_lds((const __attribute__((address_space(1))) void*)g,
                                   (__attribute__((address_space(3))) void*)lds, 16, 0, 0);
}

// ------- merged prep: 4 weight transposes + x cast, one launch -------
// ranges: qkv 3072 | out 1024 | w1 4096 | w2 4096 | cast 4096  (total 16384 blocks)
// cast range: 1024 elements per block (256 thr x float4) -> 4096*1024 = 4.19M = |x|.
__global__ __launch_bounds__(256)
void prep_all(const float* __restrict__ s0, __bf16* __restrict__ d0,
              const float* __restrict__ s1, __bf16* __restrict__ d1,
              const float* __restrict__ s2, __bf16* __restrict__ d2,
              const float* __restrict__ s3, __bf16* __restrict__ d3,
              const float* __restrict__ xf, __bf16* __restrict__ xb)
{
  __shared__ __bf16 tile[32][33];
  int id = blockIdx.x;
  if (id >= 12288) {                      // direct cast range
    id -= 12288;
    const int base = id * 1024 + threadIdx.x * 4;
    const float4 v = *(const float4*)(xf + base);
    __bf16* o = xb + base;
    o[0] = (__bf16)v.x; o[1] = (__bf16)v.y; o[2] = (__bf16)v.z; o[3] = (__bf16)v.w;
    return;
  }
  const float* in; __bf16* out; int R, C, bx, by;
  if (id < 3072)      { in = s0; out = d0; R = 1024; C = 3072; bx = id % 96;  by = id / 96; }
  else if (id < 4096) { id -= 3072; in = s1; out = d1; R = 1024; C = 1024; bx = id % 32;  by = id / 32; }
  else if (id < 8192) { id -= 4096; in = s2; out = d2; R = 1024; C = 4096; bx = id % 128; by = id / 128; }
  else                { id -= 8192; in = s3; out = d3; R = 4096; C = 1024; bx = id % 32;  by = id / 32; }
  const int bc = bx * 32, br = by * 32;
  const int lx = threadIdx.x & 31, ly = threadIdx.x >> 5;
#pragma unroll
  for (int p = 0; p < 4; ++p)
    tile[ly + p * 8][lx] = (__bf16)in[(size_t)(br + ly + p * 8) * C + bc + lx];
  __syncthreads();
#pragma unroll
  for (int p = 0; p < 4; ++p)
    out[(size_t)(bc + ly + p * 8) * R + br + lx] = tile[lx][ly + p * 8];
}

// ---------------- V transpose (bf16): qkv [B*S][3072] -> vtg [BH][64][2048] ----------------
__global__ __launch_bounds__(256)
void vtrans(const __bf16* __restrict__ qkv, __bf16* __restrict__ vtg)
{
  __shared__ __bf16 tile[32][33];
  const int sx = blockIdx.x * 32;
  const int dy = blockIdx.y * 32;
  const int z = blockIdx.z;
  const int b = z >> 4, h = z & 15;
  const int lx = threadIdx.x & 31, ly = threadIdx.x >> 5;
  const __bf16* src = qkv + (size_t)b * 2048 * 3072 + 2048 + h * 64;
#pragma unroll
  for (int p = 0; p < 4; ++p)
    tile[ly + p * 8][lx] = src[(size_t)(sx + ly + p * 8) * 3072 + dy + lx];
  __syncthreads();
  __bf16* dst = vtg + (size_t)z * 64 * 2048;
#pragma unroll
  for (int p = 0; p < 4; ++p)
    dst[(size_t)(dy + ly + p * 8) * 2048 + sx + lx] = tile[lx][ly + p * 8];
}

// ========= 2-phase dbuf MFMA GEMM (16x16x32, proven), parametric BN (BK=64) ==============
template<int BN, bool OUT_BF16, bool RELU, bool RESID, bool RBF16, bool SPLIT>
__global__ __launch_bounds__(256)
void gemm_bt(const __bf16* __restrict__ A, const __bf16* __restrict__ Bt,
             const float* __restrict__ bias, const void* __restrict__ residv,
             void* __restrict__ C0v, void* __restrict__ C1v,
             int M, int N, int Kfull, int Ksub)
{
  constexpr int BK = 64;
  constexpr int NW = BN / 32;
  constexpr int CH = BK / 8;
  __shared__ __bf16 As[2][128 * BK];
  __shared__ __bf16 Bs[2][BN * BK];
  const int tid = threadIdx.x;
  const int wave = tid >> 6, lane = tid & 63;
  const int g = lane >> 4, l16 = lane & 15;
  const int row0 = blockIdx.x * 128, col0 = blockIdx.y * BN;
  const int z = SPLIT ? blockIdx.z : 0;
  const __bf16* Az = A + (size_t)z * Ksub;
  const __bf16* Bz = Bt + (size_t)z * Ksub;
  const int wr = wave >> 1, wc = wave & 1;
  f32x4 acc[4][NW] = {};
  const int nk = Ksub / BK;

  auto STAGE = [&](int buf, int k0) {
#pragma unroll
    for (int r = 0; r < 128 * CH / 256; ++r) {
      const int seg = r * 256 + tid;
      const int row = seg / CH, cp = seg % CH;
      const int src = (cp ^ (row & 7)) * 8;
      gload16(&As[buf][(r * 256 + wave * 64) * 8], &Az[(size_t)(row0 + row) * Kfull + k0 + src]);
    }
#pragma unroll
    for (int r = 0; r < BN * CH / 256; ++r) {
      const int seg = r * 256 + tid;
      const int row = seg / CH, cp = seg % CH;
      const int src = (cp ^ (row & 7)) * 8;
      gload16(&Bs[buf][(r * 256 + wave * 64) * 8], &Bz[(size_t)(col0 + row) * Kfull + k0 + src]);
    }
  };

  STAGE(0, 0);
  __syncthreads();
  int cur = 0;
  for (int t = 0; t < nk; ++t) {
    if (t + 1 < nk) STAGE(cur ^ 1, (t + 1) * BK);
#pragma unroll
    for (int kk = 0; kk < 2; ++kk) {
      bf16x8 af[4], bfr[NW];
#pragma unroll
      for (int m = 0; m < 4; ++m) {
        const int row = wr * 64 + m * 16 + l16;
        af[m] = *(const bf16x8*)&As[cur][row * BK + (((kk * 4 + g) ^ (row & 7)) << 3)];
      }
#pragma unroll
      for (int n = 0; n < NW; ++n) {
        const int row = wc * (BN / 2) + n * 16 + l16;
        bfr[n] = *(const bf16x8*)&Bs[cur][row * BK + (((kk * 4 + g) ^ (row & 7)) << 3)];
      }
#pragma unroll
      for (int m = 0; m < 4; ++m)
#pragma unroll
        for (int n = 0; n < NW; ++n)
          acc[m][n] = __builtin_amdgcn_mfma_f32_16x16x32_bf16(af[m], bfr[n], acc[m][n], 0, 0, 0);
    }
    __syncthreads();
    cur ^= 1;
  }
#pragma unroll
  for (int n = 0; n < NW; ++n) {
    const int col = col0 + wc * (BN / 2) + n * 16 + l16;
    float bv = 0.f;
    if (!SPLIT || z == 0) bv = bias[col];
#pragma unroll
    for (int m = 0; m < 4; ++m) {
      const int rrow = row0 + wr * 64 + m * 16 + g * 4;
#pragma unroll
      for (int r = 0; r < 4; ++r) {
        float v = acc[m][n][r] + bv;
        const size_t idx = (size_t)(rrow + r) * N + col;
        if (RESID && (!SPLIT || z == 0)) {
          if (RBF16) v += (float)((const __bf16*)residv)[idx];
          else       v += ((const float*)residv)[idx];
        }
        if (SPLIT) {
          ((__bf16*)(z ? C1v : C0v))[idx] = (__bf16)v;
        } else {
          if (RELU)  v = fmaxf(v, 0.f);
          if (OUT_BF16) ((__bf16*)C0v)[idx] = (__bf16)v;
          else          ((float*)C0v)[idx] = v;
        }
      }
    }
  }
}

// ---------------- flash attention (causal), swapped-QK^T, no-max softmax ------------------
// grid (32 bh, 32 y); balanced qi permutation; 40 KB LDS -> 4 blocks/CU.
__global__ __launch_bounds__(256)
void attn_fwd(const __bf16* __restrict__ qkv, const __bf16* __restrict__ vtg,
              __bf16* __restrict__ ctx)
{
  constexpr int S = 2048, H = 1024, W3 = 3 * H;
  __shared__ __bf16 Ks[2][64 * 64];
  __shared__ __bf16 Vt[2][64 * 64];
  __shared__ __bf16 Ps[4][16 * 64];
  const int tid = threadIdx.x, wave = tid >> 6, lane = tid & 63;
  const int g = lane >> 4, l16 = lane & 15;
  const int perm = ((l16 & 7) << 1) | (l16 >> 3);
  const int bh = blockIdx.x;
  const int y = blockIdx.y, j = y & 7, m = y >> 3;
  const int qi = (m == 0) ? (31 - j) : (m == 1) ? (16 + j) : (m == 2) ? (15 - j) : j;
  const int b = bh >> 4, h = bh & 15;
  const size_t base = (size_t)b * S * W3;
  const __bf16* Qg = qkv + base;
  const __bf16* Kg = qkv + base + H;
  const __bf16* Vg = vtg + (size_t)bh * 64 * S;

  auto STAGE_KV = [&](int buf, int kv0) {
#pragma unroll
    for (int r = 0; r < 2; ++r) {
      const int seg = r * 256 + tid;
      const int row = seg >> 3;
      const int ko = ((seg & 7) ^ (row & 7)) * 8;
      gload16(&Ks[buf][(r * 256 + wave * 64) * 8], &Kg[(size_t)(kv0 + row) * W3 + h * 64 + ko]);
      gload16(&Vt[buf][(r * 256 + wave * 64) * 8], &Vg[(size_t)row * S + kv0 + ko]);
    }
  };

  const int q0 = qi * 64;
  const int qrow = q0 + wave * 16 + l16;
  bf16x8 qa[2];
#pragma unroll
  for (int kk = 0; kk < 2; ++kk)
    qa[kk] = *(const bf16x8*)&Qg[(size_t)qrow * W3 + h * 64 + kk * 32 + g * 8];

  f32x4 o[4] = {};
  float lsum = 0.f;
  const int nT = qi + 1;

  STAGE_KV(0, 0);
  __syncthreads();
  int cur = 0;

  for (int t = 0; t < nT; ++t) {
    const int kv0 = t * 64;
    if (t + 1 < nT) STAGE_KV(cur ^ 1, kv0 + 64);

    f32x4 s[4] = {};
    __builtin_amdgcn_s_setprio(1);
#pragma unroll
    for (int kk = 0; kk < 2; ++kk) {
      bf16x8 kb[4];
#pragma unroll
      for (int n = 0; n < 4; ++n) {
        const int row = n * 16 + l16;
        kb[n] = *(const bf16x8*)&Ks[cur][row * 64 + ((kk * 32 + g * 8) ^ ((row & 7) << 3))];
      }
#pragma unroll
      for (int n = 0; n < 4; ++n)
        s[n] = __builtin_amdgcn_mfma_f32_16x16x32_bf16(kb[n], qa[kk], s[n], 0, 0, 0);
    }
    __builtin_amdgcn_s_setprio(0);

    const bool diag = (t == nT - 1);
#pragma unroll
    for (int n = 0; n < 4; ++n) {
      float lp[4];
#pragma unroll
      for (int r = 0; r < 4; ++r) {
        const int ka = kv0 + n * 16 + g * 4 + r;
        float p = exp2f(s[n][r] * 0.18033688f);
        if (diag && ka > qrow) p = 0.f;
        lp[r] = p;
        lsum += p;
      }
      bf16x4 pk;
      pk[0] = (__bf16)lp[0]; pk[1] = (__bf16)lp[1];
      pk[2] = (__bf16)lp[2]; pk[3] = (__bf16)lp[3];
      *(bf16x4*)&Ps[wave][l16 * 64 + (((4 * n + g) ^ perm) << 2)] = pk;
    }

    __builtin_amdgcn_s_setprio(1);
#pragma unroll
    for (int kk = 0; kk < 2; ++kk) {
      const int hb = 8 * kk + 2 * g;
      bf16x4 p0 = *(const bf16x4*)&Ps[wave][l16 * 64 + ((hb ^ perm) << 2)];
      bf16x4 p1 = *(const bf16x4*)&Ps[wave][l16 * 64 + (((hb + 1) ^ perm) << 2)];
      bf16x8 pa = __builtin_shufflevector(p0, p1, 0, 1, 2, 3, 4, 5, 6, 7);
      bf16x8 vb[4];
#pragma unroll
      for (int n2 = 0; n2 < 4; ++n2) {
        const int row = n2 * 16 + l16;
        vb[n2] = *(const bf16x8*)&Vt[cur][row * 64 + ((kk * 32 + g * 8) ^ ((row & 7) << 3))];
      }
#pragma unroll
      for (int n2 = 0; n2 < 4; ++n2)
        o[n2] = __builtin_amdgcn_mfma_f32_16x16x32_bf16(pa, vb[n2], o[n2], 0, 0, 0);
    }
    __builtin_amdgcn_s_setprio(0);
    __syncthreads();
    cur ^= 1;
  }

  lsum += __shfl_xor(lsum, 16);
  lsum += __shfl_xor(lsum, 32);
#pragma unroll
  for (int r = 0; r < 4; ++r) {
    const float den = __shfl(lsum, g * 4 + r);
    const float inv = 1.f / den;
    const int qr = q0 + wave * 16 + g * 4 + r;
#pragma unroll
    for (int n2 = 0; n2 < 4; ++n2) {
      const int d = n2 * 16 + l16;
      ctx[(size_t)(b * S + qr) * H + h * 64 + d] = (__bf16)(o[n2][r] * inv);
    }
  }
}

// ---------------- LayerNorm, bf16 input(s): 1-input -> bf16 out; 2-input -> fp32 out ------
template<bool TWO_IN>
__global__ __launch_bounds__(256)
void lnb_kernel(const __bf16* __restrict__ in, const __bf16* __restrict__ in2,
                const float* __restrict__ gw, const float* __restrict__ bw,
                float* __restrict__ outf, __bf16* __restrict__ outb)
{
  const int row = blockIdx.x, tid = threadIdx.x;
  const bf16x4 a = ((const bf16x4*)(in + (size_t)row * 1024))[tid];
  float4 xv;
  xv.x = (float)a[0]; xv.y = (float)a[1]; xv.z = (float)a[2]; xv.w = (float)a[3];
  if (TWO_IN) {
    const bf16x4 b = ((const bf16x4*)(in2 + (size_t)row * 1024))[tid];
    xv.x += (float)b[0]; xv.y += (float)b[1]; xv.z += (float)b[2]; xv.w += (float)b[3];
  }
  float s = xv.x + xv.y + xv.z + xv.w;
  float s2 = xv.x * xv.x + xv.y * xv.y + xv.z * xv.z + xv.w * xv.w;
#pragma unroll
  for (int off = 32; off; off >>= 1) { s += __shfl_xor(s, off); s2 += __shfl_xor(s2, off); }
  __shared__ float ps[8];
  if ((tid & 63) == 0) { ps[tid >> 6] = s; ps[4 + (tid >> 6)] = s2; }
  __syncthreads();
  s = ps[0] + ps[1] + ps[2] + ps[3];
  s2 = ps[4] + ps[5] + ps[6] + ps[7];
  const float mean = s * (1.f / 1024.f);
  const float var = s2 * (1.f / 1024.f) - mean * mean;
  const float rs = rsqrtf(var + 1e-5f);
  const float4 gv = ((const float4*)gw)[tid];
  const float4 bv = ((const float4*)bw)[tid];
  float4 y;
  y.x = (xv.x - mean) * rs * gv.x + bv.x;
  y.y = (xv.y - mean) * rs * gv.y + bv.y;
  y.z = (xv.z - mean) * rs * gv.z + bv.z;
  y.w = (xv.w - mean) * rs * gv.w + bv.w;
  if (TWO_IN) {
    ((float4*)(outf + (size_t)row * 1024))[tid] = y;
  } else {
    __bf16* ob = outb + (size_t)row * 1024 + tid * 4;
    ob[0] = (__bf16)y.x; ob[1] = (__bf16)y.y; ob[2] = (__bf16)y.z; ob[3] = (__bf16)y.w;
  }
}

extern "C" void kernel_launch(void* const* d_in, const int* in_sizes, int n_in,
                              void* d_out, int out_size, void* d_ws, size_t ws_size,
                              hipStream_t stream)
{
  (void)in_sizes; (void)n_in; (void)out_size; (void)ws_size;
  const float* x     = (const float*)d_in[0];
  const float* qkv_w = (const float*)d_in[2];
  const float* qkv_b = (const float*)d_in[3];
  const float* out_w = (const float*)d_in[4];
  const float* out_b = (const float*)d_in[5];
  const float* w1    = (const float*)d_in[6];
  const float* b1    = (const float*)d_in[7];
  const float* w2    = (const float*)d_in[8];
  const float* b2    = (const float*)d_in[9];
  const float* ln1g  = (const float*)d_in[10];
  const float* ln1b  = (const float*)d_in[11];
  const float* ln2g  = (const float*)d_in[12];
  const float* ln2b  = (const float*)d_in[13];

  char* ws = (char*)d_ws;
  __bf16* wt_qkv = (__bf16*)(ws + 0);          // [3072][1024]  dead after QKV
  __bf16* wt_out = (__bf16*)(ws + 6291456);    // [1024][1024]  dead after out-proj
  __bf16* wt_w1  = (__bf16*)(ws + 8388608);    // [4096][1024]  dead after FFN1
  __bf16* wt_w2  = (__bf16*)(ws + 16777216);   // [1024][4096]  live through FFN2
  __bf16* xb     = (__bf16*)(ws + 25165824);   // x bf16, then ctx
  __bf16* big    = (__bf16*)(ws + 33554432);   // qkv, then h1
  float*  res    = (float*)(ws + 67108864);    // vtg, then res1(bf16), then pz0
  __bf16* x1b    = (__bf16*)(ws + 100663296);  // ln1 out bf16 (FFN1 A + FFN2 resid)
  __bf16* vtg    = (__bf16*)res;               // [32][64][2048] (dead after attn)
  __bf16* resb   = (__bf16*)res;               // res1 bf16 (8MB; vtg dead after attn)
  __bf16* pz0    = (__bf16*)res;               // FFN2 partial z=0 (8MB; resb dead post-LN1)
  __bf16* pz1    = (__bf16*)ws;                // FFN2 partial z=1 (8MB over dead weights)

  prep_all<<<16384, 256, 0, stream>>>(qkv_w, wt_qkv, out_w, wt_out, w1, wt_w1, w2, wt_w2,
                                      x, xb);

  // QKV: BN=128, grid 32x24
  gemm_bt<128, true, false, false, false, false><<<dim3(32, 24), 256, 0, stream>>>(
      xb, wt_qkv, qkv_b, nullptr, big, nullptr, 4096, 3072, 1024, 1024);
  // V -> V^T per (b,h)
  vtrans<<<dim3(64, 2, 32), 256, 0, stream>>>(big, vtg);
  // attention -> ctx (reuses xb); 1024 balanced blocks, 4/CU
  attn_fwd<<<dim3(32, 32), 256, 0, stream>>>(big, vtg, xb);
  // out-proj + residual(x fp32) -> resb bf16 ; BN=64, grid 32x16
  gemm_bt<64, true, false, true, false, false><<<dim3(32, 16), 256, 0, stream>>>(
      xb, wt_out, out_b, x, resb, nullptr, 4096, 1024, 1024, 1024);
  // LN1 (bf16 in) -> x1b bf16
  lnb_kernel<false><<<4096, 256, 0, stream>>>(resb, nullptr, ln1g, ln1b, nullptr, x1b);
  // FFN1 + ReLU: BN=128, grid 32x32 -> h1 bf16
  gemm_bt<128, true, true, false, false, false><<<dim3(32, 32), 256, 0, stream>>>(
      x1b, wt_w1, b1, nullptr, big, nullptr, 4096, 4096, 1024, 1024);
  // FFN2 + residual(x1b bf16): split-K=2, grid 32x8x2 -> bf16 partials pz0, pz1
  gemm_bt<128, false, false, true, true, true><<<dim3(32, 8, 2), 256, 0, stream>>>(
      big, wt_w2, b2, x1b, pz0, pz1, 4096, 1024, 4096, 2048);
  // LN2 (combines bf16 partials) -> d_out
  lnb_kernel<true><<<4096, 256, 0, stream>>>(pz0, pz1, ln2g, ln2b, (float*)d_out, nullptr);
}